// Round 8
// baseline (549.812 us; speedup 1.0000x reference)
//
#include <hip/hip_runtime.h>
#include <cstdint>

// ---------------------------------------------------------------------------
// GCN: 3 x [ h = relu( Ahat (h W) + b ) ], then log_softmax.
// Round 8: CSR build via one-digit bucket sort. Bin pass scans edges once,
// LDS-histograms into 8 contiguous-dst-range queues (block-bump-allocated,
// coalesced uint2 writes). Count/fill passes then stream the compacted
// queues; their atomics/writes live in 50KB/0.8MB per-partition regions that
// stay L2-resident for the short burst -> kills the 72MB write amplification
// of the scatter build. Queues alias gA (dead until GEMM-0).
// Aggregate: half-wave per node, edge loop unrolled x8. GEMM rows pre-scaled
// by dis. edge_index arrives as int32 (harness converts integer inputs).
// ---------------------------------------------------------------------------

#define D 128
#define NPART 8
#define BIN_T 8
#define BIN_BLOCK_EDGES 2048   // 256 threads * BIN_T
#define QCHUNK 4096

typedef __attribute__((ext_vector_type(8))) short bf16x8;
typedef __attribute__((ext_vector_type(4))) float f32x4;

__device__ inline ushort f_to_bf(float f) {
    uint x = __float_as_uint(f);
    return (ushort)((x + 0x7fffu + ((x >> 16) & 1u)) >> 16);   // RNE
}
__device__ inline uint pack_bf2(float a, float b) {
    return (uint)f_to_bf(a) | ((uint)f_to_bf(b) << 16);
}
__device__ inline float bf_lo(uint u) { return __uint_as_float(u << 16); }
__device__ inline float bf_hi(uint u) { return __uint_as_float(u & 0xffff0000u); }

// ---------------- CSR build ----------------

__global__ void zero_ints(int* __restrict__ a, int n) {
    int i = blockIdx.x * 256 + threadIdx.x;
    if (i < n) a[i] = 0;
}

// single scan: bin edges into NPART queues by dst range (p = d / part_sz)
__global__ void bin_edges(const int* __restrict__ ei, uint2* __restrict__ queue,
                          int* __restrict__ qtail, int E, int part_sz, int qcap) {
    __shared__ int lcnt[NPART], lbase[NPART];
    int tid = threadIdx.x;
    if (tid < NPART) lcnt[tid] = 0;
    __syncthreads();
    int e0 = blockIdx.x * BIN_BLOCK_EDGES;
    int d[BIN_T], s[BIN_T], p[BIN_T], r[BIN_T];
#pragma unroll
    for (int t = 0; t < BIN_T; t++) {
        int e = e0 + t * 256 + tid;
        if (e < E) {
            d[t] = ei[(size_t)E + e];
            s[t] = ei[e];
            p[t] = d[t] / part_sz;
            r[t] = atomicAdd(&lcnt[p[t]], 1);
        } else {
            p[t] = -1;
        }
    }
    __syncthreads();
    if (tid < NPART) lbase[tid] = atomicAdd(&qtail[tid], lcnt[tid]);
    __syncthreads();
#pragma unroll
    for (int t = 0; t < BIN_T; t++) {
        if (p[t] >= 0)
            queue[(size_t)p[t] * qcap + lbase[p[t]] + r[t]] = make_uint2((uint)d[t], (uint)s[t]);
    }
}

// per-partition degree count from compacted queue (cnt region ~50KB/partition)
__global__ void count_from_queue(const uint2* __restrict__ queue, const int* __restrict__ qtail,
                                 int* __restrict__ cnt, int qcap) {
    int p = blockIdx.x & (NPART - 1);
    int c = blockIdx.x >> 3;
    int len = qtail[p];
    int i0 = c * QCHUNK;
    int i1 = min(i0 + QCHUNK, len);
    const uint2* q = queue + (size_t)p * qcap;
    for (int i = i0 + threadIdx.x; i < i1; i += 256)
        atomicAdd(&cnt[q[i].x], 1);
}

__global__ void compute_dis(const int* __restrict__ cnt, float* __restrict__ dis, int n) {
    int i = blockIdx.x * 256 + threadIdx.x;
    if (i < n) dis[i] = rsqrtf((float)(cnt[i] + 1));   // self loop -> deg >= 1
}

__global__ void scan_block(const int* __restrict__ cnt, int* __restrict__ rowptr,
                           int* __restrict__ blocksum, int n) {
    __shared__ int s[256];
    int t = threadIdx.x;
    int i = blockIdx.x * 256 + t;
    int v = (i < n) ? cnt[i] : 0;
    s[t] = v;
    __syncthreads();
    for (int off = 1; off < 256; off <<= 1) {
        int u = (t >= off) ? s[t - off] : 0;
        __syncthreads();
        s[t] += u;
        __syncthreads();
    }
    if (i < n) rowptr[i] = s[t] - v;
    if (t == 255) blocksum[blockIdx.x] = s[255];
}

__global__ void scan_sums(const int* __restrict__ blocksum, int* __restrict__ blockoff, int nb) {
    __shared__ int s[512];
    int t = threadIdx.x;
    int carry = 0;
    for (int base = 0; base < nb; base += 512) {
        int idx = base + t;
        int v = (idx < nb) ? blocksum[idx] : 0;
        s[t] = v;
        __syncthreads();
        for (int off = 1; off < 512; off <<= 1) {
            int u = (t >= off) ? s[t - off] : 0;
            __syncthreads();
            s[t] += u;
            __syncthreads();
        }
        if (idx < nb) blockoff[idx] = carry + s[t] - v;
        carry += s[511];
        __syncthreads();
    }
}

__global__ void add_offsets(int* __restrict__ rowptr, const int* __restrict__ blockoff,
                            int n, int E) {
    int i = blockIdx.x * 256 + threadIdx.x;
    if (i < n) rowptr[i] += blockoff[i >> 8];
    if (i == 0) rowptr[n] = E;
}

// per-partition fill from compacted queue (col region ~0.8MB/partition)
__global__ void fill_from_queue(const uint2* __restrict__ queue, const int* __restrict__ qtail,
                                const int* __restrict__ rowptr, int* __restrict__ rank,
                                int* __restrict__ col, int qcap) {
    int p = blockIdx.x & (NPART - 1);
    int c = blockIdx.x >> 3;
    int len = qtail[p];
    int i0 = c * QCHUNK;
    int i1 = min(i0 + QCHUNK, len);
    const uint2* q = queue + (size_t)p * qcap;
    for (int i = i0 + threadIdx.x; i < i1; i += 256) {
        uint2 e = q[i];
        int slot = rowptr[e.x] + atomicAdd(&rank[e.x], 1);
        col[slot] = (int)e.y;
    }
}

// W fp32 [k][n] -> Wt bf16 [n][k]
__global__ void convert_w(const float* __restrict__ W, ushort* __restrict__ Wt) {
    int i = blockIdx.x * 256 + threadIdx.x;   // 16384
    int k = i >> 7, nn = i & 127;
    Wt[nn * D + k] = f_to_bf(W[i]);
}

// ---------------- GEMM: G[n,128] = dis[row] * (X[n,128] @ W), MFMA ----------
template <int F32IN>
__global__ __launch_bounds__(256)
void gemm_mfma(const void* __restrict__ Xv, const ushort* __restrict__ Wt,
               const float* __restrict__ dis, ushort* __restrict__ G, int n) {
    int tid = threadIdx.x;
    int wave = tid >> 6, lane = tid & 63;
    int lr = lane & 15, quad = lane >> 4;
    int rowbase = blockIdx.x * 128 + wave * 32;

    int ar0 = min(rowbase + lr, n - 1);
    int ar1 = min(rowbase + 16 + lr, n - 1);

    f32x4 acc[2][8];
#pragma unroll
    for (int rt = 0; rt < 2; rt++)
#pragma unroll
        for (int nt = 0; nt < 8; nt++) acc[rt][nt] = (f32x4){0.f, 0.f, 0.f, 0.f};

#pragma unroll
    for (int kk = 0; kk < 4; kk++) {
        bf16x8 b[8];
#pragma unroll
        for (int nt = 0; nt < 8; nt++)
            b[nt] = ((const bf16x8*)(Wt + (size_t)(nt * 16 + lr) * D))[kk * 4 + quad];

        bf16x8 a0, a1;
        if (F32IN) {
            const float* X = (const float*)Xv;
            const float* p0 = X + (size_t)ar0 * D + kk * 32 + quad * 8;
            const float* p1 = X + (size_t)ar1 * D + kk * 32 + quad * 8;
            float4 u0 = ((const float4*)p0)[0], v0 = ((const float4*)p0)[1];
            float4 u1 = ((const float4*)p1)[0], v1 = ((const float4*)p1)[1];
            a0 = (bf16x8){(short)f_to_bf(u0.x), (short)f_to_bf(u0.y), (short)f_to_bf(u0.z), (short)f_to_bf(u0.w),
                          (short)f_to_bf(v0.x), (short)f_to_bf(v0.y), (short)f_to_bf(v0.z), (short)f_to_bf(v0.w)};
            a1 = (bf16x8){(short)f_to_bf(u1.x), (short)f_to_bf(u1.y), (short)f_to_bf(u1.z), (short)f_to_bf(u1.w),
                          (short)f_to_bf(v1.x), (short)f_to_bf(v1.y), (short)f_to_bf(v1.z), (short)f_to_bf(v1.w)};
        } else {
            const ushort* X = (const ushort*)Xv;
            a0 = ((const bf16x8*)(X + (size_t)ar0 * D))[kk * 4 + quad];
            a1 = ((const bf16x8*)(X + (size_t)ar1 * D))[kk * 4 + quad];
        }
#pragma unroll
        for (int nt = 0; nt < 8; nt++) {
            acc[0][nt] = __builtin_amdgcn_mfma_f32_16x16x32_bf16(a0, b[nt], acc[0][nt], 0, 0, 0);
            acc[1][nt] = __builtin_amdgcn_mfma_f32_16x16x32_bf16(a1, b[nt], acc[1][nt], 0, 0, 0);
        }
    }

    // epilogue: C col=lane&15, row=quad*4+reg; scale row by dis[row]
#pragma unroll
    for (int rt = 0; rt < 2; rt++) {
#pragma unroll
        for (int r = 0; r < 4; r++) {
            int row = rowbase + rt * 16 + quad * 4 + r;
            if (row < n) {
                float dsc = dis[row];
#pragma unroll
                for (int nt = 0; nt < 8; nt++)
                    G[(size_t)row * D + nt * 16 + lr] = f_to_bf(dsc * acc[rt][nt][r]);
            }
        }
    }
}

// ---------------- Aggregation ----------------
// G rows pre-scaled by dis[src]. out[i] = act( dis[i]*(sum G[s] + G[i]) + b ).
// Half-wave (32 lanes, uint2=4 bf16 per lane) per node; edge loop unrolled x8.
template <int MODE>
__global__ __launch_bounds__(256)
void aggregate(const ushort* __restrict__ Gv, const float* __restrict__ dis,
               const int* __restrict__ rowptr, const int* __restrict__ col,
               const float* __restrict__ bias, void* __restrict__ outv, int n) {
    int node = blockIdx.x * 8 + (threadIdx.x >> 5);
    if (node >= n) return;
    int lane = threadIdx.x & 31;
    const uint2* base = (const uint2*)Gv;

    uint2 u = base[(size_t)node * 32 + lane];
    float ax = bf_lo(u.x), ay = bf_hi(u.x), az = bf_lo(u.y), aw = bf_hi(u.y);

    int beg = rowptr[node], end = rowptr[node + 1];
    int j = beg;
    for (; j + 8 <= end; j += 8) {
        int s0 = col[j],     s1 = col[j + 1], s2 = col[j + 2], s3 = col[j + 3];
        int s4 = col[j + 4], s5 = col[j + 5], s6 = col[j + 6], s7 = col[j + 7];
        uint2 v0 = base[(size_t)s0 * 32 + lane];
        uint2 v1 = base[(size_t)s1 * 32 + lane];
        uint2 v2 = base[(size_t)s2 * 32 + lane];
        uint2 v3 = base[(size_t)s3 * 32 + lane];
        uint2 v4 = base[(size_t)s4 * 32 + lane];
        uint2 v5 = base[(size_t)s5 * 32 + lane];
        uint2 v6 = base[(size_t)s6 * 32 + lane];
        uint2 v7 = base[(size_t)s7 * 32 + lane];
        ax += bf_lo(v0.x) + bf_lo(v1.x) + bf_lo(v2.x) + bf_lo(v3.x)
            + bf_lo(v4.x) + bf_lo(v5.x) + bf_lo(v6.x) + bf_lo(v7.x);
        ay += bf_hi(v0.x) + bf_hi(v1.x) + bf_hi(v2.x) + bf_hi(v3.x)
            + bf_hi(v4.x) + bf_hi(v5.x) + bf_hi(v6.x) + bf_hi(v7.x);
        az += bf_lo(v0.y) + bf_lo(v1.y) + bf_lo(v2.y) + bf_lo(v3.y)
            + bf_lo(v4.y) + bf_lo(v5.y) + bf_lo(v6.y) + bf_lo(v7.y);
        aw += bf_hi(v0.y) + bf_hi(v1.y) + bf_hi(v2.y) + bf_hi(v3.y)
            + bf_hi(v4.y) + bf_hi(v5.y) + bf_hi(v6.y) + bf_hi(v7.y);
    }
    for (; j < end; j++) {
        uint2 v = base[(size_t)col[j] * 32 + lane];
        ax += bf_lo(v.x); ay += bf_hi(v.x); az += bf_lo(v.y); aw += bf_hi(v.y);
    }

    float di = dis[node];
    float4 b = ((const float4*)bias)[lane];
    ax = fmaxf(di * ax + b.x, 0.f);
    ay = fmaxf(di * ay + b.y, 0.f);
    az = fmaxf(di * az + b.z, 0.f);
    aw = fmaxf(di * aw + b.w, 0.f);

    if (MODE == 1) {
        float m = fmaxf(fmaxf(ax, ay), fmaxf(az, aw));
        for (int off = 16; off > 0; off >>= 1) m = fmaxf(m, __shfl_xor(m, off, 32));
        float e = __expf(ax - m) + __expf(ay - m) + __expf(az - m) + __expf(aw - m);
        for (int off = 16; off > 0; off >>= 1) e += __shfl_xor(e, off, 32);
        float ls = m + __logf(e);
        ((float4*)outv)[(size_t)node * 32 + lane] = make_float4(ax - ls, ay - ls, az - ls, aw - ls);
    } else {
        ((uint2*)outv)[(size_t)node * 32 + lane] = make_uint2(pack_bf2(ax, ay), pack_bf2(az, aw));
    }
}

// ---------------- launcher ----------------

static inline size_t align256(size_t x) { return (x + 255) & ~(size_t)255; }

extern "C" void kernel_launch(void* const* d_in, const int* in_sizes, int n_in,
                              void* d_out, int out_size, void* d_ws, size_t ws_size,
                              hipStream_t stream) {
    const float* x  = (const float*)d_in[0];
    const int*   ei = (const int*)d_in[1];      // int32 (harness-converted)
    const float* W0 = (const float*)d_in[2];
    const float* W1 = (const float*)d_in[3];
    const float* W2 = (const float*)d_in[4];
    const float* b0 = (const float*)d_in[5];
    const float* b1 = (const float*)d_in[6];
    const float* b2 = (const float*)d_in[7];
    float* out      = (float*)d_out;

    const int N = in_sizes[0] / D;
    const int E = in_sizes[1] / 2;

    const int NA = ((N + 63) / 64) * 64;            // 256B-aligned int count
    const int part_sz = (N + NPART - 1) / NPART;    // contiguous dst range per partition
    const int qcap = E / NPART + 25000;             // >>50 sigma slack (uniform dst)

    // workspace (~59 MB)
    char* ws = (char*)d_ws;
    size_t off = 0;
    int*    cnt      = (int*)(ws + off);    // [NA]      \  zeroed together
    int*    rank     = cnt + NA;            // [NA]       |
    int*    qtail    = rank + NA;           // [NPART]   /
    off = align256(off + ((size_t)2 * NA + NPART) * 4);
    float*  dis      = (float*)(ws + off);  off = align256(off + (size_t)N * 4);
    int*    rowptr   = (int*)(ws + off);    off = align256(off + ((size_t)N + 1) * 4);
    int*    blocksum = (int*)(ws + off);    off = align256(off + 4096);
    int*    blockoff = (int*)(ws + off);    off = align256(off + 4096);
    ushort* Wt0      = (ushort*)(ws + off); off = align256(off + (size_t)D * D * 2);
    ushort* Wt1      = (ushort*)(ws + off); off = align256(off + (size_t)D * D * 2);
    ushort* Wt2      = (ushort*)(ws + off); off = align256(off + (size_t)D * D * 2);
    int*    col      = (int*)(ws + off);    off = align256(off + (size_t)E * 4);
    ushort* xb       = (ushort*)(ws + off); off = align256(off + (size_t)N * D * 2);
    ushort* gA       = (ushort*)(ws + off); off = align256(off + (size_t)N * D * 2);
    ushort* hb       = (ushort*)d_out;      // first 25.6 MB of d_out; dead before final write
    uint2*  queue    = (uint2*)gA;          // 8*qcap*8B = 14.4MB, dead before GEMM-0
    (void)ws_size;

    const int nbN = (N + 255) / 256;
    const int binBlocks = (E + BIN_BLOCK_EDGES - 1) / BIN_BLOCK_EDGES;
    const int qBlocks   = ((qcap + QCHUNK - 1) / QCHUNK) * NPART;

    // --- CSR build (bucket sort by dst range) ---
    zero_ints<<<(2 * NA + NPART + 255) / 256, 256, 0, stream>>>(cnt, 2 * NA + NPART);
    bin_edges<<<binBlocks, 256, 0, stream>>>(ei, queue, qtail, E, part_sz, qcap);
    count_from_queue<<<qBlocks, 256, 0, stream>>>(queue, qtail, cnt, qcap);
    compute_dis<<<nbN, 256, 0, stream>>>(cnt, dis, N);
    scan_block<<<nbN, 256, 0, stream>>>(cnt, rowptr, blocksum, N);
    scan_sums<<<1, 512, 0, stream>>>(blocksum, blockoff, nbN);
    add_offsets<<<nbN, 256, 0, stream>>>(rowptr, blockoff, N, E);
    fill_from_queue<<<qBlocks, 256, 0, stream>>>(queue, qtail, rowptr, rank, col, qcap);

    // --- weight conversions ---
    convert_w<<<64, 256, 0, stream>>>(W0, Wt0);
    convert_w<<<64, 256, 0, stream>>>(W1, Wt1);
    convert_w<<<64, 256, 0, stream>>>(W2, Wt2);

    const int gemmBlocks = (N + 127) / 128;
    const int aggBlocks  = (N + 7) / 8;

    // --- layer 0: x(fp32) -> gA -> hb ---
    gemm_mfma<1><<<gemmBlocks, 256, 0, stream>>>(x, Wt0, dis, gA, N);
    aggregate<0><<<aggBlocks, 256, 0, stream>>>(gA, dis, rowptr, col, b0, hb, N);
    // --- layer 1: hb -> gA -> xb ---
    gemm_mfma<0><<<gemmBlocks, 256, 0, stream>>>(hb, Wt1, dis, gA, N);
    aggregate<0><<<aggBlocks, 256, 0, stream>>>(gA, dis, rowptr, col, b1, xb, N);
    // --- layer 2: xb -> gA -> out (fp32, log_softmax) ---
    gemm_mfma<0><<<gemmBlocks, 256, 0, stream>>>(xb, Wt2, dis, gA, N);
    aggregate<1><<<aggBlocks, 256, 0, stream>>>(gA, dis, rowptr, col, b2, out, N);
}

// Round 9
// 432.195 us; speedup vs baseline: 1.2721x; 1.2721x over previous
//
#include <hip/hip_runtime.h>
#include <cstdint>

// ---------------------------------------------------------------------------
// GCN: 3 x [ h = relu( Ahat (h W) + b ) ], then log_softmax.
// Round 9: atomic-free CSR build. Evidence r5-r8: any kernel doing ~1.6M
// device-scope atomics costs ~70-130us and 60-105MB of fabric writes no
// matter how it's partitioned (atomics RMW at memory side, bypassing L2).
// Replacement: histogram sort. (1) per-block LDS histogram over 782 dst
// buckets -> table; (2) column scan + bucket-base scan = exact offsets;
// (3) scatter via LDS-bumped precomputed offsets (globally unique, no global
// atomics); (4) per-bucket finalize: LDS count/scan -> rowptr+dis, LDS-rank
// scatter of src into an L1-resident 8KB col window. Queue aliases gA.
// Aggregate: half-wave per node, x8 unroll. GEMM: MFMA, rows pre-scaled by
// dis. edge_index arrives as int32 (harness converts integer inputs).
// ---------------------------------------------------------------------------

#define D 128
#define NBMAX 800      // max dst buckets of 128 nodes (N <= 102400)
#define ACHUNK 8192    // edges per histogram/scatter block

typedef __attribute__((ext_vector_type(8))) short bf16x8;
typedef __attribute__((ext_vector_type(4))) float f32x4;

__device__ inline ushort f_to_bf(float f) {
    uint x = __float_as_uint(f);
    return (ushort)((x + 0x7fffu + ((x >> 16) & 1u)) >> 16);   // RNE
}
__device__ inline uint pack_bf2(float a, float b) {
    return (uint)f_to_bf(a) | ((uint)f_to_bf(b) << 16);
}
__device__ inline float bf_lo(uint u) { return __uint_as_float(u << 16); }
__device__ inline float bf_hi(uint u) { return __uint_as_float(u & 0xffff0000u); }

// ---------------- CSR build (no global atomics) ----------------

// per-block LDS histogram of dst>>7
__global__ void hist_pass(const int* __restrict__ ei, int* __restrict__ hist,
                          int E, int NB) {
    __shared__ int lh[NBMAX];
    for (int i = threadIdx.x; i < NB; i += 256) lh[i] = 0;
    __syncthreads();
    int e0 = blockIdx.x * ACHUNK;
    int e1 = min(e0 + ACHUNK, E);
    for (int e = e0 + threadIdx.x; e < e1; e += 256)
        atomicAdd(&lh[ei[(size_t)E + e] >> 7], 1);
    __syncthreads();
    int* hrow = hist + (size_t)blockIdx.x * NB;
    for (int i = threadIdx.x; i < NB; i += 256) hrow[i] = lh[i];
}

// exclusive scan down each bucket column (B blocks' entries); emit totals
__global__ void col_scan(int* __restrict__ hist, int* __restrict__ btotal,
                         int B, int NB) {
    __shared__ int s[256];
    int g = blockIdx.x;
    int t = threadIdx.x;
    int v = (t < B) ? hist[(size_t)t * NB + g] : 0;
    s[t] = v;
    __syncthreads();
    for (int off = 1; off < 256; off <<= 1) {
        int u = (t >= off) ? s[t - off] : 0;
        __syncthreads();
        s[t] += u;
        __syncthreads();
    }
    if (t < B) hist[(size_t)t * NB + g] = s[t] - v;   // exclusive within column
    if (t == 255) btotal[g] = s[255];
}

// exclusive scan of bucket totals -> bucket bases (single block, NB<=1024)
__global__ void base_scan(const int* __restrict__ btotal, int* __restrict__ bbase,
                          int NB, int E) {
    __shared__ int s[1024];
    int t = threadIdx.x;
    int v = (t < NB) ? btotal[t] : 0;
    s[t] = v;
    __syncthreads();
    for (int off = 1; off < 1024; off <<= 1) {
        int u = (t >= off) ? s[t - off] : 0;
        __syncthreads();
        s[t] += u;
        __syncthreads();
    }
    if (t < NB) bbase[t] = s[t] - v;
    if (t == 0) bbase[NB] = E;
}

// scatter (d,src) into bucket-major queue; slots = LDS bump of exact offsets
__global__ void scatter_pass(const int* __restrict__ ei, const int* __restrict__ hist,
                             const int* __restrict__ bbase, uint2* __restrict__ queue,
                             int E, int NB) {
    __shared__ int loff[NBMAX];
    const int* hrow = hist + (size_t)blockIdx.x * NB;
    for (int i = threadIdx.x; i < NB; i += 256) loff[i] = bbase[i] + hrow[i];
    __syncthreads();
    int e0 = blockIdx.x * ACHUNK;
    int e1 = min(e0 + ACHUNK, E);
    for (int e = e0 + threadIdx.x; e < e1; e += 256) {
        int d = ei[(size_t)E + e];
        int s = ei[e];
        int slot = atomicAdd(&loff[d >> 7], 1);   // LDS atomic
        queue[slot] = make_uint2((uint)d, (uint)s);
    }
}

// per-bucket: count 128 nodes, scan, rowptr+dis, scatter src into col
__global__ void finalize_pass(const uint2* __restrict__ queue, const int* __restrict__ bbase,
                              int* __restrict__ rowptr, float* __restrict__ dis,
                              int* __restrict__ col, int N, int NB) {
    __shared__ int cnt[128], pre[128], run[128];
    int g = blockIdx.x;
    int t = threadIdx.x;
    int base = bbase[g], next = bbase[g + 1];
    if (t < 128) { cnt[t] = 0; run[t] = 0; }
    __syncthreads();
    for (int i = base + t; i < next; i += 256)
        atomicAdd(&cnt[queue[i].x & 127], 1);     // LDS atomic
    __syncthreads();
    if (t < 128) pre[t] = cnt[t];
    __syncthreads();
    for (int off = 1; off < 128; off <<= 1) {
        int u = (t < 128 && t >= off) ? pre[t - off] : 0;
        __syncthreads();
        if (t < 128) pre[t] += u;                 // inclusive scan
        __syncthreads();
    }
    if (t < 128) {
        int node = (g << 7) + t;
        if (node < N) {
            rowptr[node] = base + pre[t] - cnt[t];
            dis[node] = rsqrtf((float)(cnt[t] + 1));   // self loop -> deg >= 1
        }
    }
    if (g == NB - 1 && t == 0) rowptr[N] = next;  // == E
    __syncthreads();
    for (int i = base + t; i < next; i += 256) {
        uint2 e = queue[i];
        int idx = (int)(e.x & 127);
        int r = atomicAdd(&run[idx], 1);          // LDS atomic
        col[base + pre[idx] - cnt[idx] + r] = (int)e.y;
    }
}

// W fp32 [k][n] -> Wt bf16 [n][k], all three weights in one launch
__global__ void convert_w3(const float* __restrict__ W0, const float* __restrict__ W1,
                           const float* __restrict__ W2, ushort* __restrict__ Wt0,
                           ushort* __restrict__ Wt1, ushort* __restrict__ Wt2) {
    int which = blockIdx.x >> 6;   // 64 blocks (16384 elems) per weight
    int i = (blockIdx.x & 63) * 256 + threadIdx.x;
    const float* W = which == 0 ? W0 : (which == 1 ? W1 : W2);
    ushort* Wt = which == 0 ? Wt0 : (which == 1 ? Wt1 : Wt2);
    int k = i >> 7, nn = i & 127;
    Wt[nn * D + k] = f_to_bf(W[i]);
}

// ---------------- GEMM: G[n,128] = dis[row] * (X[n,128] @ W), MFMA ----------
template <int F32IN>
__global__ __launch_bounds__(256)
void gemm_mfma(const void* __restrict__ Xv, const ushort* __restrict__ Wt,
               const float* __restrict__ dis, ushort* __restrict__ G, int n) {
    int tid = threadIdx.x;
    int wave = tid >> 6, lane = tid & 63;
    int lr = lane & 15, quad = lane >> 4;
    int rowbase = blockIdx.x * 128 + wave * 32;

    int ar0 = min(rowbase + lr, n - 1);
    int ar1 = min(rowbase + 16 + lr, n - 1);

    f32x4 acc[2][8];
#pragma unroll
    for (int rt = 0; rt < 2; rt++)
#pragma unroll
        for (int nt = 0; nt < 8; nt++) acc[rt][nt] = (f32x4){0.f, 0.f, 0.f, 0.f};

#pragma unroll
    for (int kk = 0; kk < 4; kk++) {
        bf16x8 b[8];
#pragma unroll
        for (int nt = 0; nt < 8; nt++)
            b[nt] = ((const bf16x8*)(Wt + (size_t)(nt * 16 + lr) * D))[kk * 4 + quad];

        bf16x8 a0, a1;
        if (F32IN) {
            const float* X = (const float*)Xv;
            const float* p0 = X + (size_t)ar0 * D + kk * 32 + quad * 8;
            const float* p1 = X + (size_t)ar1 * D + kk * 32 + quad * 8;
            float4 u0 = ((const float4*)p0)[0], v0 = ((const float4*)p0)[1];
            float4 u1 = ((const float4*)p1)[0], v1 = ((const float4*)p1)[1];
            a0 = (bf16x8){(short)f_to_bf(u0.x), (short)f_to_bf(u0.y), (short)f_to_bf(u0.z), (short)f_to_bf(u0.w),
                          (short)f_to_bf(v0.x), (short)f_to_bf(v0.y), (short)f_to_bf(v0.z), (short)f_to_bf(v0.w)};
            a1 = (bf16x8){(short)f_to_bf(u1.x), (short)f_to_bf(u1.y), (short)f_to_bf(u1.z), (short)f_to_bf(u1.w),
                          (short)f_to_bf(v1.x), (short)f_to_bf(v1.y), (short)f_to_bf(v1.z), (short)f_to_bf(v1.w)};
        } else {
            const ushort* X = (const ushort*)Xv;
            a0 = ((const bf16x8*)(X + (size_t)ar0 * D))[kk * 4 + quad];
            a1 = ((const bf16x8*)(X + (size_t)ar1 * D))[kk * 4 + quad];
        }
#pragma unroll
        for (int nt = 0; nt < 8; nt++) {
            acc[0][nt] = __builtin_amdgcn_mfma_f32_16x16x32_bf16(a0, b[nt], acc[0][nt], 0, 0, 0);
            acc[1][nt] = __builtin_amdgcn_mfma_f32_16x16x32_bf16(a1, b[nt], acc[1][nt], 0, 0, 0);
        }
    }

    // epilogue: C col=lane&15, row=quad*4+reg; scale row by dis[row]
#pragma unroll
    for (int rt = 0; rt < 2; rt++) {
#pragma unroll
        for (int r = 0; r < 4; r++) {
            int row = rowbase + rt * 16 + quad * 4 + r;
            if (row < n) {
                float dsc = dis[row];
#pragma unroll
                for (int nt = 0; nt < 8; nt++)
                    G[(size_t)row * D + nt * 16 + lr] = f_to_bf(dsc * acc[rt][nt][r]);
            }
        }
    }
}

// ---------------- Aggregation ----------------
// G rows pre-scaled by dis[src]. out[i] = act( dis[i]*(sum G[s] + G[i]) + b ).
// Half-wave (32 lanes, uint2=4 bf16 per lane) per node; edge loop unrolled x8.
template <int MODE>
__global__ __launch_bounds__(256)
void aggregate(const ushort* __restrict__ Gv, const float* __restrict__ dis,
               const int* __restrict__ rowptr, const int* __restrict__ col,
               const float* __restrict__ bias, void* __restrict__ outv, int n) {
    int node = blockIdx.x * 8 + (threadIdx.x >> 5);
    if (node >= n) return;
    int lane = threadIdx.x & 31;
    const uint2* base = (const uint2*)Gv;

    uint2 u = base[(size_t)node * 32 + lane];
    float ax = bf_lo(u.x), ay = bf_hi(u.x), az = bf_lo(u.y), aw = bf_hi(u.y);

    int beg = rowptr[node], end = rowptr[node + 1];
    int j = beg;
    for (; j + 8 <= end; j += 8) {
        int s0 = col[j],     s1 = col[j + 1], s2 = col[j + 2], s3 = col[j + 3];
        int s4 = col[j + 4], s5 = col[j + 5], s6 = col[j + 6], s7 = col[j + 7];
        uint2 v0 = base[(size_t)s0 * 32 + lane];
        uint2 v1 = base[(size_t)s1 * 32 + lane];
        uint2 v2 = base[(size_t)s2 * 32 + lane];
        uint2 v3 = base[(size_t)s3 * 32 + lane];
        uint2 v4 = base[(size_t)s4 * 32 + lane];
        uint2 v5 = base[(size_t)s5 * 32 + lane];
        uint2 v6 = base[(size_t)s6 * 32 + lane];
        uint2 v7 = base[(size_t)s7 * 32 + lane];
        ax += bf_lo(v0.x) + bf_lo(v1.x) + bf_lo(v2.x) + bf_lo(v3.x)
            + bf_lo(v4.x) + bf_lo(v5.x) + bf_lo(v6.x) + bf_lo(v7.x);
        ay += bf_hi(v0.x) + bf_hi(v1.x) + bf_hi(v2.x) + bf_hi(v3.x)
            + bf_hi(v4.x) + bf_hi(v5.x) + bf_hi(v6.x) + bf_hi(v7.x);
        az += bf_lo(v0.y) + bf_lo(v1.y) + bf_lo(v2.y) + bf_lo(v3.y)
            + bf_lo(v4.y) + bf_lo(v5.y) + bf_lo(v6.y) + bf_lo(v7.y);
        aw += bf_hi(v0.y) + bf_hi(v1.y) + bf_hi(v2.y) + bf_hi(v3.y)
            + bf_hi(v4.y) + bf_hi(v5.y) + bf_hi(v6.y) + bf_hi(v7.y);
    }
    for (; j < end; j++) {
        uint2 v = base[(size_t)col[j] * 32 + lane];
        ax += bf_lo(v.x); ay += bf_hi(v.x); az += bf_lo(v.y); aw += bf_hi(v.y);
    }

    float di = dis[node];
    float4 b = ((const float4*)bias)[lane];
    ax = fmaxf(di * ax + b.x, 0.f);
    ay = fmaxf(di * ay + b.y, 0.f);
    az = fmaxf(di * az + b.z, 0.f);
    aw = fmaxf(di * aw + b.w, 0.f);

    if (MODE == 1) {
        float m = fmaxf(fmaxf(ax, ay), fmaxf(az, aw));
        for (int off = 16; off > 0; off >>= 1) m = fmaxf(m, __shfl_xor(m, off, 32));
        float e = __expf(ax - m) + __expf(ay - m) + __expf(az - m) + __expf(aw - m);
        for (int off = 16; off > 0; off >>= 1) e += __shfl_xor(e, off, 32);
        float ls = m + __logf(e);
        ((float4*)outv)[(size_t)node * 32 + lane] = make_float4(ax - ls, ay - ls, az - ls, aw - ls);
    } else {
        ((uint2*)outv)[(size_t)node * 32 + lane] = make_uint2(pack_bf2(ax, ay), pack_bf2(az, aw));
    }
}

// ---------------- launcher ----------------

static inline size_t align256(size_t x) { return (x + 255) & ~(size_t)255; }

extern "C" void kernel_launch(void* const* d_in, const int* in_sizes, int n_in,
                              void* d_out, int out_size, void* d_ws, size_t ws_size,
                              hipStream_t stream) {
    const float* x  = (const float*)d_in[0];
    const int*   ei = (const int*)d_in[1];      // int32 (harness-converted)
    const float* W0 = (const float*)d_in[2];
    const float* W1 = (const float*)d_in[3];
    const float* W2 = (const float*)d_in[4];
    const float* b0 = (const float*)d_in[5];
    const float* b1 = (const float*)d_in[6];
    const float* b2 = (const float*)d_in[7];
    float* out      = (float*)d_out;

    const int N = in_sizes[0] / D;
    const int E = in_sizes[1] / 2;

    const int NB = (N + 127) >> 7;                    // dst buckets (<= NBMAX)
    const int B  = (E + ACHUNK - 1) / ACHUNK;         // histogram blocks (<= 256)

    // workspace (~59 MB)
    char* ws = (char*)d_ws;
    size_t off = 0;
    float*  dis      = (float*)(ws + off);  off = align256(off + (size_t)N * 4);
    int*    rowptr   = (int*)(ws + off);    off = align256(off + ((size_t)N + 1) * 4);
    int*    hist     = (int*)(ws + off);    off = align256(off + (size_t)B * NB * 4);
    int*    btotal   = (int*)(ws + off);    off = align256(off + ((size_t)NB + 1) * 4);
    int*    bbase    = (int*)(ws + off);    off = align256(off + ((size_t)NB + 1) * 4);
    ushort* Wt0      = (ushort*)(ws + off); off = align256(off + (size_t)D * D * 2);
    ushort* Wt1      = (ushort*)(ws + off); off = align256(off + (size_t)D * D * 2);
    ushort* Wt2      = (ushort*)(ws + off); off = align256(off + (size_t)D * D * 2);
    int*    col      = (int*)(ws + off);    off = align256(off + (size_t)E * 4);
    ushort* xb       = (ushort*)(ws + off); off = align256(off + (size_t)N * D * 2);
    ushort* gA       = (ushort*)(ws + off); off = align256(off + (size_t)N * D * 2);
    ushort* hb       = (ushort*)d_out;      // first 25.6 MB of d_out; dead before final write
    uint2*  queue    = (uint2*)gA;          // E*8B = 12.8MB, dead before GEMM-0
    (void)ws_size;

    // --- CSR build (histogram sort, no global atomics) ---
    hist_pass<<<B, 256, 0, stream>>>(ei, hist, E, NB);
    col_scan<<<NB, 256, 0, stream>>>(hist, btotal, B, NB);
    base_scan<<<1, 1024, 0, stream>>>(btotal, bbase, NB, E);
    scatter_pass<<<B, 256, 0, stream>>>(ei, hist, bbase, queue, E, NB);
    finalize_pass<<<NB, 256, 0, stream>>>(queue, bbase, rowptr, dis, col, N, NB);

    // --- weight conversions (one launch) ---
    convert_w3<<<192, 256, 0, stream>>>(W0, W1, W2, Wt0, Wt1, Wt2);

    const int gemmBlocks = (N + 127) / 128;
    const int aggBlocks  = (N + 7) / 8;

    // --- layer 0: x(fp32) -> gA -> hb ---
    gemm_mfma<1><<<gemmBlocks, 256, 0, stream>>>(x, Wt0, dis, gA, N);
    aggregate<0><<<aggBlocks, 256, 0, stream>>>(gA, dis, rowptr, col, b0, hb, N);
    // --- layer 1: hb -> gA -> xb ---
    gemm_mfma<0><<<gemmBlocks, 256, 0, stream>>>(hb, Wt1, dis, gA, N);
    aggregate<0><<<aggBlocks, 256, 0, stream>>>(gA, dis, rowptr, col, b1, xb, N);
    // --- layer 2: xb -> gA -> out (fp32, log_softmax) ---
    gemm_mfma<0><<<gemmBlocks, 256, 0, stream>>>(xb, Wt2, dis, gA, N);
    aggregate<1><<<aggBlocks, 256, 0, stream>>>(gA, dis, rowptr, col, b2, out, N);
}

// Round 10
// 402.141 us; speedup vs baseline: 1.3672x; 1.0747x over previous
//
#include <hip/hip_runtime.h>
#include <cstdint>

// ---------------------------------------------------------------------------
// GCN: 3 x [ h = relu( Ahat (h W) + b ) ], then log_softmax.
// Round 10: (a) aggregate uses a QUARTER-wave (16 lanes x uint4) per node,
// edge loop unrolled x8 -> 8 KB of gathers in flight per wave (fixes the
// latency-limited 3.5 TB/s of r9's half-wave uint2); (b) GEMM stages Wt in
// LDS in frag-major swizzled order (lane-contiguous ds_read_b128, conflict-
// free) so B-frag reads stop contending with streaming A in L1.
// CSR build: r9's atomic-free histogram sort (unchanged).
// edge_index arrives as int32 (harness converts integer inputs).
// ---------------------------------------------------------------------------

#define D 128
#define NBMAX 800      // max dst buckets of 128 nodes (N <= 102400)
#define ACHUNK 8192    // edges per histogram/scatter block

typedef __attribute__((ext_vector_type(8))) short bf16x8;
typedef __attribute__((ext_vector_type(4))) float f32x4;

__device__ inline ushort f_to_bf(float f) {
    uint x = __float_as_uint(f);
    return (ushort)((x + 0x7fffu + ((x >> 16) & 1u)) >> 16);   // RNE
}
__device__ inline uint pack_bf2(float a, float b) {
    return (uint)f_to_bf(a) | ((uint)f_to_bf(b) << 16);
}
__device__ inline float bf_lo(uint u) { return __uint_as_float(u << 16); }
__device__ inline float bf_hi(uint u) { return __uint_as_float(u & 0xffff0000u); }

// ---------------- CSR build (no global atomics) ----------------

__global__ void hist_pass(const int* __restrict__ ei, int* __restrict__ hist,
                          int E, int NB) {
    __shared__ int lh[NBMAX];
    for (int i = threadIdx.x; i < NB; i += 256) lh[i] = 0;
    __syncthreads();
    int e0 = blockIdx.x * ACHUNK;
    int e1 = min(e0 + ACHUNK, E);
    for (int e = e0 + threadIdx.x; e < e1; e += 256)
        atomicAdd(&lh[ei[(size_t)E + e] >> 7], 1);
    __syncthreads();
    int* hrow = hist + (size_t)blockIdx.x * NB;
    for (int i = threadIdx.x; i < NB; i += 256) hrow[i] = lh[i];
}

__global__ void col_scan(int* __restrict__ hist, int* __restrict__ btotal,
                         int B, int NB) {
    __shared__ int s[256];
    int g = blockIdx.x;
    int t = threadIdx.x;
    int v = (t < B) ? hist[(size_t)t * NB + g] : 0;
    s[t] = v;
    __syncthreads();
    for (int off = 1; off < 256; off <<= 1) {
        int u = (t >= off) ? s[t - off] : 0;
        __syncthreads();
        s[t] += u;
        __syncthreads();
    }
    if (t < B) hist[(size_t)t * NB + g] = s[t] - v;   // exclusive within column
    if (t == 255) btotal[g] = s[255];
}

__global__ void base_scan(const int* __restrict__ btotal, int* __restrict__ bbase,
                          int NB, int E) {
    __shared__ int s[1024];
    int t = threadIdx.x;
    int v = (t < NB) ? btotal[t] : 0;
    s[t] = v;
    __syncthreads();
    for (int off = 1; off < 1024; off <<= 1) {
        int u = (t >= off) ? s[t - off] : 0;
        __syncthreads();
        s[t] += u;
        __syncthreads();
    }
    if (t < NB) bbase[t] = s[t] - v;
    if (t == 0) bbase[NB] = E;
}

__global__ void scatter_pass(const int* __restrict__ ei, const int* __restrict__ hist,
                             const int* __restrict__ bbase, uint2* __restrict__ queue,
                             int E, int NB) {
    __shared__ int loff[NBMAX];
    const int* hrow = hist + (size_t)blockIdx.x * NB;
    for (int i = threadIdx.x; i < NB; i += 256) loff[i] = bbase[i] + hrow[i];
    __syncthreads();
    int e0 = blockIdx.x * ACHUNK;
    int e1 = min(e0 + ACHUNK, E);
    for (int e = e0 + threadIdx.x; e < e1; e += 256) {
        int d = ei[(size_t)E + e];
        int s = ei[e];
        int slot = atomicAdd(&loff[d >> 7], 1);   // LDS atomic
        queue[slot] = make_uint2((uint)d, (uint)s);
    }
}

__global__ void finalize_pass(const uint2* __restrict__ queue, const int* __restrict__ bbase,
                              int* __restrict__ rowptr, float* __restrict__ dis,
                              int* __restrict__ col, int N, int NB) {
    __shared__ int cnt[128], pre[128], run[128];
    int g = blockIdx.x;
    int t = threadIdx.x;
    int base = bbase[g], next = bbase[g + 1];
    if (t < 128) { cnt[t] = 0; run[t] = 0; }
    __syncthreads();
    for (int i = base + t; i < next; i += 256)
        atomicAdd(&cnt[queue[i].x & 127], 1);     // LDS atomic
    __syncthreads();
    if (t < 128) pre[t] = cnt[t];
    __syncthreads();
    for (int off = 1; off < 128; off <<= 1) {
        int u = (t < 128 && t >= off) ? pre[t - off] : 0;
        __syncthreads();
        if (t < 128) pre[t] += u;                 // inclusive scan
        __syncthreads();
    }
    if (t < 128) {
        int node = (g << 7) + t;
        if (node < N) {
            rowptr[node] = base + pre[t] - cnt[t];
            dis[node] = rsqrtf((float)(cnt[t] + 1));   // self loop -> deg >= 1
        }
    }
    if (g == NB - 1 && t == 0) rowptr[N] = next;  // == E
    __syncthreads();
    for (int i = base + t; i < next; i += 256) {
        uint2 e = queue[i];
        int idx = (int)(e.x & 127);
        int r = atomicAdd(&run[idx], 1);          // LDS atomic
        col[base + pre[idx] - cnt[idx] + r] = (int)e.y;
    }
}

// W fp32 [k][n] -> Wt bf16 [n][k], all three weights in one launch
__global__ void convert_w3(const float* __restrict__ W0, const float* __restrict__ W1,
                           const float* __restrict__ W2, ushort* __restrict__ Wt0,
                           ushort* __restrict__ Wt1, ushort* __restrict__ Wt2) {
    int which = blockIdx.x >> 6;   // 64 blocks (16384 elems) per weight
    int i = (blockIdx.x & 63) * 256 + threadIdx.x;
    const float* W = which == 0 ? W0 : (which == 1 ? W1 : W2);
    ushort* Wt = which == 0 ? Wt0 : (which == 1 ? Wt1 : Wt2);
    int k = i >> 7, nn = i & 127;
    Wt[nn * D + k] = f_to_bf(W[i]);
}

// ---------------- GEMM: G[n,128] = dis[row] * (X[n,128] @ W), MFMA ----------
// 256 threads = 4 waves; wave computes 32 rows x 128 cols. Wt staged once per
// block into LDS in frag-major swizzled order: slot s = (kk*8+nt)*64 + lane
// holds the 16B b-frag that lane needs -> lane-contiguous conflict-free
// ds_read_b128 in the K-loop (B off the L1 path entirely).
template <int F32IN>
__global__ __launch_bounds__(256)
void gemm_mfma(const void* __restrict__ Xv, const ushort* __restrict__ Wt,
               const float* __restrict__ dis, ushort* __restrict__ G, int n) {
    __shared__ ushort Bs[32 * 64 * 8];   // 32 KB
    int tid = threadIdx.x;
    int wave = tid >> 6, lane = tid & 63;
    int lr = lane & 15, quad = lane >> 4;
    int rowbase = blockIdx.x * 128 + wave * 32;

    // stage Wt -> Bs (2048 slots of 16B)
    for (int s = tid; s < 2048; s += 256) {
        int g = s >> 6, l = s & 63;
        int kk = g >> 3, nt = g & 7;
        int srow = nt * 16 + (l & 15);
        int scol = kk * 32 + (l >> 4) * 8;
        ((uint4*)Bs)[s] = *(const uint4*)(Wt + srow * D + scol);
    }
    __syncthreads();

    int ar0 = min(rowbase + lr, n - 1);
    int ar1 = min(rowbase + 16 + lr, n - 1);

    f32x4 acc[2][8];
#pragma unroll
    for (int rt = 0; rt < 2; rt++)
#pragma unroll
        for (int nt = 0; nt < 8; nt++) acc[rt][nt] = (f32x4){0.f, 0.f, 0.f, 0.f};

#pragma unroll
    for (int kk = 0; kk < 4; kk++) {
        bf16x8 a0, a1;
        if (F32IN) {
            const float* X = (const float*)Xv;
            const float* p0 = X + (size_t)ar0 * D + kk * 32 + quad * 8;
            const float* p1 = X + (size_t)ar1 * D + kk * 32 + quad * 8;
            float4 u0 = ((const float4*)p0)[0], v0 = ((const float4*)p0)[1];
            float4 u1 = ((const float4*)p1)[0], v1 = ((const float4*)p1)[1];
            a0 = (bf16x8){(short)f_to_bf(u0.x), (short)f_to_bf(u0.y), (short)f_to_bf(u0.z), (short)f_to_bf(u0.w),
                          (short)f_to_bf(v0.x), (short)f_to_bf(v0.y), (short)f_to_bf(v0.z), (short)f_to_bf(v0.w)};
            a1 = (bf16x8){(short)f_to_bf(u1.x), (short)f_to_bf(u1.y), (short)f_to_bf(u1.z), (short)f_to_bf(u1.w),
                          (short)f_to_bf(v1.x), (short)f_to_bf(v1.y), (short)f_to_bf(v1.z), (short)f_to_bf(v1.w)};
        } else {
            const ushort* X = (const ushort*)Xv;
            a0 = ((const bf16x8*)(X + (size_t)ar0 * D))[kk * 4 + quad];
            a1 = ((const bf16x8*)(X + (size_t)ar1 * D))[kk * 4 + quad];
        }
#pragma unroll
        for (int nt = 0; nt < 8; nt++) {
            bf16x8 b = ((const bf16x8*)Bs)[(kk * 8 + nt) * 64 + lane];
            acc[0][nt] = __builtin_amdgcn_mfma_f32_16x16x32_bf16(a0, b, acc[0][nt], 0, 0, 0);
            acc[1][nt] = __builtin_amdgcn_mfma_f32_16x16x32_bf16(a1, b, acc[1][nt], 0, 0, 0);
        }
    }

    // epilogue: C col=lane&15, row=quad*4+reg; scale row by dis[row]
#pragma unroll
    for (int rt = 0; rt < 2; rt++) {
#pragma unroll
        for (int r = 0; r < 4; r++) {
            int row = rowbase + rt * 16 + quad * 4 + r;
            if (row < n) {
                float dsc = dis[row];
#pragma unroll
                for (int nt = 0; nt < 8; nt++)
                    G[(size_t)row * D + nt * 16 + lr] = f_to_bf(dsc * acc[rt][nt][r]);
            }
        }
    }
}

// ---------------- Aggregation ----------------
// G rows pre-scaled by dis[src]. out[i] = act( dis[i]*(sum G[s] + G[i]) + b ).
// QUARTER-wave (16 lanes x uint4 = 8 bf16) per node; edge loop unrolled x8
// -> 8 KB of gathers in flight per wave. MODE 0: relu->bf16. MODE 1: +lsm->f32.
template <int MODE>
__global__ __launch_bounds__(256)
void aggregate(const ushort* __restrict__ Gv, const float* __restrict__ dis,
               const int* __restrict__ rowptr, const int* __restrict__ col,
               const float* __restrict__ bias, void* __restrict__ outv, int n) {
    int node = blockIdx.x * 16 + (threadIdx.x >> 4);
    if (node >= n) return;
    int lane = threadIdx.x & 15;
    const uint4* base = (const uint4*)Gv;

    uint4 u = base[(size_t)node * 16 + lane];
    float a0 = bf_lo(u.x), a1 = bf_hi(u.x), a2 = bf_lo(u.y), a3 = bf_hi(u.y);
    float a4 = bf_lo(u.z), a5 = bf_hi(u.z), a6 = bf_lo(u.w), a7 = bf_hi(u.w);

    int beg = rowptr[node], end = rowptr[node + 1];
    int j = beg;
    for (; j + 8 <= end; j += 8) {
        uint4 v0 = base[(size_t)col[j + 0] * 16 + lane];
        uint4 v1 = base[(size_t)col[j + 1] * 16 + lane];
        uint4 v2 = base[(size_t)col[j + 2] * 16 + lane];
        uint4 v3 = base[(size_t)col[j + 3] * 16 + lane];
        uint4 v4 = base[(size_t)col[j + 4] * 16 + lane];
        uint4 v5 = base[(size_t)col[j + 5] * 16 + lane];
        uint4 v6 = base[(size_t)col[j + 6] * 16 + lane];
        uint4 v7 = base[(size_t)col[j + 7] * 16 + lane];
        a0 += bf_lo(v0.x) + bf_lo(v1.x) + bf_lo(v2.x) + bf_lo(v3.x)
            + bf_lo(v4.x) + bf_lo(v5.x) + bf_lo(v6.x) + bf_lo(v7.x);
        a1 += bf_hi(v0.x) + bf_hi(v1.x) + bf_hi(v2.x) + bf_hi(v3.x)
            + bf_hi(v4.x) + bf_hi(v5.x) + bf_hi(v6.x) + bf_hi(v7.x);
        a2 += bf_lo(v0.y) + bf_lo(v1.y) + bf_lo(v2.y) + bf_lo(v3.y)
            + bf_lo(v4.y) + bf_lo(v5.y) + bf_lo(v6.y) + bf_lo(v7.y);
        a3 += bf_hi(v0.y) + bf_hi(v1.y) + bf_hi(v2.y) + bf_hi(v3.y)
            + bf_hi(v4.y) + bf_hi(v5.y) + bf_hi(v6.y) + bf_hi(v7.y);
        a4 += bf_lo(v0.z) + bf_lo(v1.z) + bf_lo(v2.z) + bf_lo(v3.z)
            + bf_lo(v4.z) + bf_lo(v5.z) + bf_lo(v6.z) + bf_lo(v7.z);
        a5 += bf_hi(v0.z) + bf_hi(v1.z) + bf_hi(v2.z) + bf_hi(v3.z)
            + bf_hi(v4.z) + bf_hi(v5.z) + bf_hi(v6.z) + bf_hi(v7.z);
        a6 += bf_lo(v0.w) + bf_lo(v1.w) + bf_lo(v2.w) + bf_lo(v3.w)
            + bf_lo(v4.w) + bf_lo(v5.w) + bf_lo(v6.w) + bf_lo(v7.w);
        a7 += bf_hi(v0.w) + bf_hi(v1.w) + bf_hi(v2.w) + bf_hi(v3.w)
            + bf_hi(v4.w) + bf_hi(v5.w) + bf_hi(v6.w) + bf_hi(v7.w);
    }
    for (; j < end; j++) {
        uint4 v = base[(size_t)col[j] * 16 + lane];
        a0 += bf_lo(v.x); a1 += bf_hi(v.x); a2 += bf_lo(v.y); a3 += bf_hi(v.y);
        a4 += bf_lo(v.z); a5 += bf_hi(v.z); a6 += bf_lo(v.w); a7 += bf_hi(v.w);
    }

    float di = dis[node];
    float4 bA = ((const float4*)bias)[lane * 2];
    float4 bB = ((const float4*)bias)[lane * 2 + 1];
    a0 = fmaxf(di * a0 + bA.x, 0.f); a1 = fmaxf(di * a1 + bA.y, 0.f);
    a2 = fmaxf(di * a2 + bA.z, 0.f); a3 = fmaxf(di * a3 + bA.w, 0.f);
    a4 = fmaxf(di * a4 + bB.x, 0.f); a5 = fmaxf(di * a5 + bB.y, 0.f);
    a6 = fmaxf(di * a6 + bB.z, 0.f); a7 = fmaxf(di * a7 + bB.w, 0.f);

    if (MODE == 1) {
        float m = fmaxf(fmaxf(fmaxf(a0, a1), fmaxf(a2, a3)),
                        fmaxf(fmaxf(a4, a5), fmaxf(a6, a7)));
        for (int off = 8; off > 0; off >>= 1) m = fmaxf(m, __shfl_xor(m, off, 16));
        float e = __expf(a0 - m) + __expf(a1 - m) + __expf(a2 - m) + __expf(a3 - m)
                + __expf(a4 - m) + __expf(a5 - m) + __expf(a6 - m) + __expf(a7 - m);
        for (int off = 8; off > 0; off >>= 1) e += __shfl_xor(e, off, 16);
        float ls = m + __logf(e);
        ((float4*)outv)[(size_t)node * 32 + lane * 2]     = make_float4(a0 - ls, a1 - ls, a2 - ls, a3 - ls);
        ((float4*)outv)[(size_t)node * 32 + lane * 2 + 1] = make_float4(a4 - ls, a5 - ls, a6 - ls, a7 - ls);
    } else {
        ((uint4*)outv)[(size_t)node * 16 + lane] =
            make_uint4(pack_bf2(a0, a1), pack_bf2(a2, a3), pack_bf2(a4, a5), pack_bf2(a6, a7));
    }
}

// ---------------- launcher ----------------

static inline size_t align256(size_t x) { return (x + 255) & ~(size_t)255; }

extern "C" void kernel_launch(void* const* d_in, const int* in_sizes, int n_in,
                              void* d_out, int out_size, void* d_ws, size_t ws_size,
                              hipStream_t stream) {
    const float* x  = (const float*)d_in[0];
    const int*   ei = (const int*)d_in[1];      // int32 (harness-converted)
    const float* W0 = (const float*)d_in[2];
    const float* W1 = (const float*)d_in[3];
    const float* W2 = (const float*)d_in[4];
    const float* b0 = (const float*)d_in[5];
    const float* b1 = (const float*)d_in[6];
    const float* b2 = (const float*)d_in[7];
    float* out      = (float*)d_out;

    const int N = in_sizes[0] / D;
    const int E = in_sizes[1] / 2;

    const int NB = (N + 127) >> 7;                    // dst buckets (<= NBMAX)
    const int B  = (E + ACHUNK - 1) / ACHUNK;         // histogram blocks (<= 256)

    // workspace (~59 MB)
    char* ws = (char*)d_ws;
    size_t off = 0;
    float*  dis      = (float*)(ws + off);  off = align256(off + (size_t)N * 4);
    int*    rowptr   = (int*)(ws + off);    off = align256(off + ((size_t)N + 1) * 4);
    int*    hist     = (int*)(ws + off);    off = align256(off + (size_t)B * NB * 4);
    int*    btotal   = (int*)(ws + off);    off = align256(off + ((size_t)NB + 1) * 4);
    int*    bbase    = (int*)(ws + off);    off = align256(off + ((size_t)NB + 1) * 4);
    ushort* Wt0      = (ushort*)(ws + off); off = align256(off + (size_t)D * D * 2);
    ushort* Wt1      = (ushort*)(ws + off); off = align256(off + (size_t)D * D * 2);
    ushort* Wt2      = (ushort*)(ws + off); off = align256(off + (size_t)D * D * 2);
    int*    col      = (int*)(ws + off);    off = align256(off + (size_t)E * 4);
    ushort* xb       = (ushort*)(ws + off); off = align256(off + (size_t)N * D * 2);
    ushort* gA       = (ushort*)(ws + off); off = align256(off + (size_t)N * D * 2);
    ushort* hb       = (ushort*)d_out;      // first 25.6 MB of d_out; dead before final write
    uint2*  queue    = (uint2*)gA;          // E*8B = 12.8MB, dead before GEMM-0
    (void)ws_size;

    // --- CSR build (histogram sort, no global atomics) ---
    hist_pass<<<B, 256, 0, stream>>>(ei, hist, E, NB);
    col_scan<<<NB, 256, 0, stream>>>(hist, btotal, B, NB);
    base_scan<<<1, 1024, 0, stream>>>(btotal, bbase, NB, E);
    scatter_pass<<<B, 256, 0, stream>>>(ei, hist, bbase, queue, E, NB);
    finalize_pass<<<NB, 256, 0, stream>>>(queue, bbase, rowptr, dis, col, N, NB);

    // --- weight conversions (one launch) ---
    convert_w3<<<192, 256, 0, stream>>>(W0, W1, W2, Wt0, Wt1, Wt2);

    const int gemmBlocks = (N + 127) / 128;
    const int aggBlocks  = (N + 15) / 16;

    // --- layer 0: x(fp32) -> gA -> hb ---
    gemm_mfma<1><<<gemmBlocks, 256, 0, stream>>>(x, Wt0, dis, gA, N);
    aggregate<0><<<aggBlocks, 256, 0, stream>>>(gA, dis, rowptr, col, b0, hb, N);
    // --- layer 1: hb -> gA -> xb ---
    gemm_mfma<0><<<gemmBlocks, 256, 0, stream>>>(hb, Wt1, dis, gA, N);
    aggregate<0><<<aggBlocks, 256, 0, stream>>>(gA, dis, rowptr, col, b1, xb, N);
    // --- layer 2: xb -> gA -> out (fp32, log_softmax) ---
    gemm_mfma<0><<<gemmBlocks, 256, 0, stream>>>(xb, Wt2, dis, gA, N);
    aggregate<1><<<aggBlocks, 256, 0, stream>>>(gA, dis, rowptr, col, b2, out, N);
}